// Round 5
// baseline (246.974 us; speedup 1.0000x reference)
//
#include <hip/hip_runtime.h>
#include <cstdint>

#define DIN 2048
#define SCALE_F 0.35355339059327373f
#define EPS_F 1e-6f

// LDS word layout (float words):
//   [0, 3072)            : 3 data ring slots, each [8 pos][128 k] = 1024 words
//   [3072, 7168)         : 2 weight parity buffers, each {wq[8][128], wk[8][128]} = 2048 words
//   [7168, 7424)         : dummy sink for pipeline-tail loads
#define DSLOT_W 1024
#define WBUF_W  2048
#define WBASE_W 3072
#define DUMMY_W 7168
#define SMEM_W  7424

// ---- pre-kernel: transpose W_q, W_k ([2048,8] -> wt[2][8][2048]) ----
__global__ void transpose_w_kernel(const float* __restrict__ Wq,
                                   const float* __restrict__ Wk,
                                   float* __restrict__ wt) {
    int idx = blockIdx.x * 256 + threadIdx.x;   // 0..32767
    int m = idx >> 14;
    int r = idx & 16383;
    int h = r >> 11;
    int d = r & 2047;
    const float* src = m ? Wk : Wq;
    wt[m * 16384 + h * 2048 + d] = src[d * 8 + h];
}

// ---- main kernel: 1 wave per block; lane = (p = l>>3, h = l&7); 8 positions/block.
// Rows never leave HBM->LDS->reg path; dots and sumsq are lane-local; no barriers.
// Pipeline: uniform 4-instr stages [W0,W1,D0..D8] per 128-float chunk, 2 stages
// ahead, counted s_waitcnt vmcnt(8) (never 0). LDS tiles are XOR-swizzled via the
// GLOBAL source address (linear global_load_lds dest), reads use the same XOR ->
// 8-bank broadcast, conflict-free.
__global__ __launch_bounds__(64)
void router_kernel(const float* __restrict__ x, const float* __restrict__ bax,
                   const float* __restrict__ bq, const float* __restrict__ bk,
                   const float* __restrict__ wt, float* __restrict__ out,
                   int positions) {
    __shared__ float smem[SMEM_W];

    const int l = threadIdx.x;        // 0..63
    const int p = l >> 3;             // position sub-index 0..7
    const int h = l & 7;              // hidden column 0..7
    const long batch = (long)blockIdx.x * 8;
    if (batch >= positions) return;

    // per-lane issue offsets for stage instruction j: lane covers lds words
    // 256j+4l .. +3  <->  (pj = 2j + (l>>5), k4 = (l&31) ^ pj)
    int offx[4], offb[4], offw[4];
#pragma unroll
    for (int j = 0; j < 4; ++j) {
        const int pj = 2 * j + (l >> 5);
        const int sw = ((l & 31) ^ pj) << 4;               // swizzled f4 byte offset
        const int prow = (batch + pj < positions) ? pj : 0; // clamp OOB positions
        offx[j] = prow * 8192 + sw;    // x rows: 8KB stride
        offb[j] = prow * 65536 + sw;   // bax row-sets: 64KB stride
        offw[j] = pj * 8192 + sw;      // wt rows: 8KB stride (pj plays h; always valid)
    }

    const char* xc  = (const char*)x   + batch * 8192;
    const char* bc  = (const char*)bax + batch * 65536;
    const char* wtb = (const char*)wt;

    auto issueD = [&](int c, int r, int slot) {
        const char* base = (r == 0) ? (xc + c * 512) : (bc + (r - 1) * 8192 + c * 512);
#pragma unroll
        for (int j = 0; j < 4; ++j) {
            const char* g = base + ((r == 0) ? offx[j] : offb[j]);
            __builtin_amdgcn_global_load_lds(
                (const __attribute__((address_space(1))) void*)g,
                (__attribute__((address_space(3))) void*)&smem[slot * DSLOT_W + j * 256],
                16, 0, 0);
        }
    };
    auto issueW = [&](int cn, int which) {
        const char* base = wtb + which * 65536 + cn * 512;
#pragma unroll
        for (int j = 0; j < 4; ++j) {
            __builtin_amdgcn_global_load_lds(
                (const __attribute__((address_space(1))) void*)(base + offw[j]),
                (__attribute__((address_space(3))) void*)
                    &smem[WBASE_W + (cn & 1) * WBUF_W + which * 1024 + j * 256],
                16, 0, 0);
        }
    };
    auto issueDummy = [&]() {
#pragma unroll
        for (int j = 0; j < 4; ++j) {
            __builtin_amdgcn_global_load_lds(
                (const __attribute__((address_space(1))) void*)(xc + j * 256),
                (__attribute__((address_space(3))) void*)&smem[DUMMY_W + j * 64],
                4, 0, 0);
        }
    };

    // float4-split accumulators: 4 independent FMA chains per row
    float4 dv[9], sv[9];
#pragma unroll
    for (int r = 0; r < 9; ++r) {
        dv[r] = make_float4(0.f, 0.f, 0.f, 0.f);
        sv[r] = make_float4(0.f, 0.f, 0.f, 0.f);
    }

    // prologue: weights for chunk 0
    issueW(0, 0);
    issueW(0, 1);

    for (int c = 0; c < 16; ++c) {
#pragma unroll
        for (int i = 0; i < 11; ++i) {
            // issue stage (s+2): D(c, i) for i<=8, else W(c+1) / dummy on last chunk
            if (i <= 8)       issueD(c, i, i % 3);
            else if (c < 15)  issueW(c + 1, i - 9);
            else              issueDummy();

            // counted wait: 2 stages (8 loads) stay in flight; stage s complete
            asm volatile("s_waitcnt vmcnt(8)" ::: "memory");

            if (i >= 2) {
                const int r = i - 2;                       // compile-time after unroll
                const int ebw = (r % 3) * DSLOT_W + (p << 7);
                const int wbw = WBASE_W + (c & 1) * WBUF_W + (r == 0 ? 0 : 1024) + (h << 7);
#pragma unroll 8
                for (int k4 = 0; k4 < 32; ++k4) {
                    const float4 e4 = *(const float4*)&smem[ebw + ((k4 ^ p) << 2)];
                    const float4 w4 = *(const float4*)&smem[wbw + ((k4 ^ h) << 2)];
                    dv[r].x = fmaf(e4.x, w4.x, dv[r].x);
                    dv[r].y = fmaf(e4.y, w4.y, dv[r].y);
                    dv[r].z = fmaf(e4.z, w4.z, dv[r].z);
                    dv[r].w = fmaf(e4.w, w4.w, dv[r].w);
                    sv[r].x = fmaf(e4.x, e4.x, sv[r].x);
                    sv[r].y = fmaf(e4.y, e4.y, sv[r].y);
                    sv[r].z = fmaf(e4.z, e4.z, sv[r].z);
                    sv[r].w = fmaf(e4.w, e4.w, sv[r].w);
                }
            }
        }
    }

    // ---- epilogue: normalize, scores, softmax (all within the 8-lane octet) ----
    float dot[9], ss[9];
#pragma unroll
    for (int r = 0; r < 9; ++r) {
        dot[r] = (dv[r].x + dv[r].y) + (dv[r].z + dv[r].w);
        ss[r]  = (sv[r].x + sv[r].y) + (sv[r].z + sv[r].w);
    }
    const float qv  = fmaf(dot[0], rsqrtf(ss[0] + EPS_F), bq[h]);
    const float bkh = bk[h];

    float sc = 0.f;
#pragma unroll
    for (int n = 0; n < 8; ++n) {
        float kv = fmaf(dot[n + 1], rsqrtf(ss[n + 1] + EPS_F), bkh);
        float t = qv * kv;
        t += __shfl_xor(t, 1);
        t += __shfl_xor(t, 2);
        t += __shfl_xor(t, 4);
        if (n == h) sc = t;       // lane keeps score for key n == its h
    }
    sc *= SCALE_F;

    float mx = sc;
    mx = fmaxf(mx, __shfl_xor(mx, 1));
    mx = fmaxf(mx, __shfl_xor(mx, 2));
    mx = fmaxf(mx, __shfl_xor(mx, 4));
    const float ev = __expf(sc - mx);
    float den = ev;
    den += __shfl_xor(den, 1);
    den += __shfl_xor(den, 2);
    den += __shfl_xor(den, 4);

    if (batch + p < positions)
        out[(batch + p) * 8 + h] = ev / den;
}

extern "C" void kernel_launch(void* const* d_in, const int* in_sizes, int n_in,
                              void* d_out, int out_size, void* d_ws, size_t ws_size,
                              hipStream_t stream) {
    const float* x   = (const float*)d_in[0];
    const float* bax = (const float*)d_in[1];
    const float* Wq  = (const float*)d_in[2];
    const float* bq  = (const float*)d_in[3];
    const float* Wk  = (const float*)d_in[4];
    const float* bk  = (const float*)d_in[5];
    float* out = (float*)d_out;
    float* wt  = (float*)d_ws;   // needs 131072 B; harness ws is GB-scale (0xAA fills)

    const int positions = in_sizes[0] / DIN;   // B*S
    transpose_w_kernel<<<128, 256, 0, stream>>>(Wq, Wk, wt);
    const int nb = (positions + 7) / 8;
    router_kernel<<<nb, 64, 0, stream>>>(x, bax, bq, bk, wt, out, positions);
}

// Round 6
// 191.689 us; speedup vs baseline: 1.2884x; 1.2884x over previous
//
#include <hip/hip_runtime.h>
#include <cstdint>

#define DIN 2048
#define ROWS 9
#define SCALE_F 0.35355339059327373f
#define EPS_F 1e-6f

// One block = one position (grid = B*S = 8192 blocks), 512 threads, one-shot.
// Thread t owns elements [4t, 4t+4) of every 2048-float row; its weight slice
// (32 consecutive floats of each row-major [2048][8] matrix) lives in VGPRs.
// Dataflow: rows go HBM -> registers directly (no LDS staging, no read
// redundancy); all 9 row loads issue up front (deep MLP), weights (L2-hot)
// load behind them. One barrier; normalize+softmax+store in wave 0 via
// shuffles. No loop-carried state -> ~110 VGPR, 2 blocks/CU at
// __launch_bounds__(512,4); HW block turnover keeps HBM queues full.
__global__ __launch_bounds__(512, 4)
void router_kernel(const float* __restrict__ x, const float* __restrict__ bax,
                   const float* __restrict__ Wq, const float* __restrict__ bq,
                   const float* __restrict__ Wk, const float* __restrict__ bk,
                   float* __restrict__ out, int positions) {
    __shared__ float red[ROWS][8][9];   // [row][wave][h(+pad)] dot partials
    __shared__ float ssb[ROWS][8];      // [row][wave] sumsq partials

    const int t = threadIdx.x;    // 0..511
    const int w = t >> 6;         // wave 0..7
    const int lane = t & 63;
    const int kn = lane >> 3;     // key index (wave-0 tail)
    const int hh = lane & 7;      // hidden col (wave-0 tail)
    const long p = blockIdx.x;

    // ---- issue all 9 row loads first (HBM critical path, 9-deep MLP) ----
    const float4* xr = (const float4*)(x + p * (long)DIN) + t;
    const float4* br = (const float4*)(bax + p * (long)(8 * DIN)) + t;
    float4 v[ROWS];
    v[0] = xr[0];
#pragma unroll
    for (int r = 1; r < ROWS; ++r) v[r] = br[(r - 1) * (DIN / 4)];

    // ---- weight slices behind them (L2-resident after first touch) ----
    float wq[32], wk[32];
    {
        const float4* q4 = (const float4*)(Wq + 32 * t);
        const float4* k4 = (const float4*)(Wk + 32 * t);
#pragma unroll
        for (int j = 0; j < 8; ++j) {
            float4 a = q4[j];
            wq[4 * j + 0] = a.x; wq[4 * j + 1] = a.y;
            wq[4 * j + 2] = a.z; wq[4 * j + 3] = a.w;
        }
#pragma unroll
        for (int j = 0; j < 8; ++j) {
            float4 b = k4[j];
            wk[4 * j + 0] = b.x; wk[4 * j + 1] = b.y;
            wk[4 * j + 2] = b.z; wk[4 * j + 3] = b.w;
        }
    }

    float ssv[ROWS];
#pragma unroll
    for (int r = 0; r < ROWS; ++r) {
        float e[4] = { v[r].x, v[r].y, v[r].z, v[r].w };
        // sumsq partial
        ssv[r] = fmaf(e[3], e[3], fmaf(e[2], e[2], fmaf(e[1], e[1], e[0] * e[0])));

        // dot partials for all 8 hidden cols over this thread's 4 elements
        const float* wa = (r == 0) ? wq : wk;   // r is unroll-constant
        float pd[8];
#pragma unroll
        for (int h = 0; h < 8; ++h)
            pd[h] = fmaf(e[3], wa[24 + h],
                     fmaf(e[2], wa[16 + h],
                      fmaf(e[1], wa[8 + h], e[0] * wa[h])));

        // in-group-of-8 transpose reduce: 8 channels -> 1 per lane
        float r1[4];
#pragma unroll
        for (int i = 0; i < 4; ++i) {
            float keep = (lane & 1) ? pd[i + 4] : pd[i];
            float send = (lane & 1) ? pd[i] : pd[i + 4];
            r1[i] = keep + __shfl_xor(send, 1);
        }
        float r2[2];
#pragma unroll
        for (int i = 0; i < 2; ++i) {
            float keep = (lane & 2) ? r1[i + 2] : r1[i];
            float send = (lane & 2) ? r1[i] : r1[i + 2];
            r2[i] = keep + __shfl_xor(send, 2);
        }
        float keep = (lane & 4) ? r2[1] : r2[0];
        float send = (lane & 4) ? r2[0] : r2[1];
        float dv = keep + __shfl_xor(send, 4);
        // cross-group (8 groups per wave)
        dv += __shfl_xor(dv, 8);
        dv += __shfl_xor(dv, 16);
        dv += __shfl_xor(dv, 32);
        if (lane < 8)
            red[r][w][((lane & 1) << 2) | (lane & 2) | ((lane & 4) >> 2)] = dv;
    }

    // ---- sumsq reduce: rows 0..7 via one transpose-reduce, row 8 alone ----
    {
        float r1[4];
#pragma unroll
        for (int i = 0; i < 4; ++i) {
            float keep = (lane & 1) ? ssv[i + 4] : ssv[i];
            float send = (lane & 1) ? ssv[i] : ssv[i + 4];
            r1[i] = keep + __shfl_xor(send, 1);
        }
        float r2[2];
#pragma unroll
        for (int i = 0; i < 2; ++i) {
            float keep = (lane & 2) ? r1[i + 2] : r1[i];
            float send = (lane & 2) ? r1[i] : r1[i + 2];
            r2[i] = keep + __shfl_xor(send, 2);
        }
        float keep = (lane & 4) ? r2[1] : r2[0];
        float send = (lane & 4) ? r2[0] : r2[1];
        float sv = keep + __shfl_xor(send, 4);
        sv += __shfl_xor(sv, 8);
        sv += __shfl_xor(sv, 16);
        sv += __shfl_xor(sv, 32);
        if (lane < 8)
            ssb[((lane & 1) << 2) | (lane & 2) | ((lane & 4) >> 2)][w] = sv;
        float s8 = ssv[8];
#pragma unroll
        for (int m = 1; m < 64; m <<= 1) s8 += __shfl_xor(s8, m);
        if (lane == 0) ssb[8][w] = s8;
    }

    __syncthreads();   // red + ssb visible

    // ---- wave 0: normalize + scores + softmax + store, all in-wave ----
    if (w == 0) {
        float dtk = 0.f, ssk = 0.f, dtq = 0.f, ssq = 0.f;
#pragma unroll
        for (int wv = 0; wv < 8; ++wv) {
            dtk += red[kn + 1][wv][hh];
            ssk += ssb[kn + 1][wv];
            dtq += red[0][wv][hh];
            ssq += ssb[0][wv];
        }
        float kval = fmaf(dtk, rsqrtf(ssk + EPS_F), bk[hh]);
        float qval = fmaf(dtq, rsqrtf(ssq + EPS_F), bq[hh]);
        // score_kn = SCALE * sum_h q[h]*k[kn][h]
        float s = qval * kval;
        s += __shfl_xor(s, 1);
        s += __shfl_xor(s, 2);
        s += __shfl_xor(s, 4);
        s *= SCALE_F;
        // softmax across the 8 groups
        float mx = s;
        mx = fmaxf(mx, __shfl_xor(mx, 8));
        mx = fmaxf(mx, __shfl_xor(mx, 16));
        mx = fmaxf(mx, __shfl_xor(mx, 32));
        float ev = __expf(s - mx);
        float den = ev;
        den += __shfl_xor(den, 8);
        den += __shfl_xor(den, 16);
        den += __shfl_xor(den, 32);
        if (hh == 0) out[p * 8 + kn] = ev / den;
    }
}

extern "C" void kernel_launch(void* const* d_in, const int* in_sizes, int n_in,
                              void* d_out, int out_size, void* d_ws, size_t ws_size,
                              hipStream_t stream) {
    const float* x   = (const float*)d_in[0];
    const float* bax = (const float*)d_in[1];
    const float* Wq  = (const float*)d_in[2];
    const float* bq  = (const float*)d_in[3];
    const float* Wk  = (const float*)d_in[4];
    const float* bk  = (const float*)d_in[5];
    float* out = (float*)d_out;

    const int positions = in_sizes[0] / DIN;   // B*S
    router_kernel<<<positions, 512, 0, stream>>>(x, bax, Wq, bq, Wk, bk, out, positions);
}